// Round 6
// baseline (980.376 us; speedup 1.0000x reference)
//
#include <hip/hip_runtime.h>
#include <hip/hip_bf16.h>

// ---------------------------------------------------------------------------
// 2-layer GCN:  out = GCNConv(GCNConv(x, W1), W2)  with shared edge_index.
//   deg[i] = 1 + indeg(i);  dis[i] = rsqrt(deg[i])
//   layer: out[i] = dis[i]^2*h[i] + sum_{e:dst=i} dis[src]*dis[i]*h[src]
// CSR path: histogram -> scan -> fill (built once, used by both layers),
// then per-node register accumulation (no f32 atomics).
// ---------------------------------------------------------------------------

#define N_NODES 100000
#define F_IN 512
#define F_OUT 16
#define WS_PAD 516   // 512 + 4 floats padding: lane stride 516 -> bank (4*l+k)%32, 2-way max

// ---- GEMM1: h[N,16] = x[N,512] @ W[512,16], shfl-broadcast ----------------
// 16 lanes per row. Lane l loads 8 disjoint float4 (coalesced 256B/group),
// broadcasts via __shfl(width=16). W staged transposed [16][516] in LDS.
__global__ __launch_bounds__(256) void k_gemm1(const float* __restrict__ x,
                                               const float* __restrict__ W,
                                               float* __restrict__ h, int nrows) {
    __shared__ __align__(16) float Ws[F_OUT * WS_PAD];  // ~33 KB
    for (int i = threadIdx.x; i < F_IN * F_OUT; i += 256) {
        int k = i >> 4, o = i & 15;
        Ws[o * WS_PAD + k] = W[i];                      // WsT[o][k] = W[k][o]
    }
    __syncthreads();

    int l = threadIdx.x & 15;
    int r = blockIdx.x * 16 + (threadIdx.x >> 4);
    if (r >= nrows) return;

    const float4* xr = (const float4*)(x + (size_t)r * F_IN);
    float4 v[8];
#pragma unroll
    for (int c = 0; c < 8; ++c) v[c] = xr[c * 16 + l];  // coalesced, 1/16 the loads

    const float* wrow = Ws + l * WS_PAD;
    float acc = 0.0f;
#pragma unroll
    for (int c = 0; c < 8; ++c) {
#pragma unroll
        for (int t = 0; t < 16; ++t) {
            float4 wv = *(const float4*)(wrow + c * 64 + t * 4);  // ds_read_b128, <=2-way
            float ax = __shfl(v[c].x, t, 16);
            float ay = __shfl(v[c].y, t, 16);
            float az = __shfl(v[c].z, t, 16);
            float aw = __shfl(v[c].w, t, 16);
            acc = fmaf(ax, wv.x, acc);
            acc = fmaf(ay, wv.y, acc);
            acc = fmaf(az, wv.z, acc);
            acc = fmaf(aw, wv.w, acc);
        }
    }
    h[(size_t)r * 16 + l] = acc;
}

// ---- small GEMM2: h2[N,16] = a[N,16] @ W2[16,16] --------------------------
__global__ __launch_bounds__(256) void k_gemm2(const float* __restrict__ a,
                                               const float* __restrict__ W,
                                               float* __restrict__ h2, int nrows) {
    __shared__ float Ws[F_OUT * 17];                    // WsT[o][k], padded
    if (threadIdx.x < 256) {
        int i = threadIdx.x;
        int k = i >> 4, o = i & 15;
        Ws[o * 17 + k] = W[i];
    }
    __syncthreads();
    int l = threadIdx.x & 15;
    int r = blockIdx.x * 16 + (threadIdx.x >> 4);
    if (r >= nrows) return;
    float av = a[(size_t)r * 16 + l];                   // coalesced, 1 load/thread
    const float* wrow = Ws + l * 17;
    float acc = 0.0f;
#pragma unroll
    for (int t = 0; t < 16; ++t) {
        float xv = __shfl(av, t, 16);
        acc = fmaf(xv, wrow[t], acc);
    }
    h2[(size_t)r * 16 + l] = acc;
}

// ---- CSR build ------------------------------------------------------------
__global__ void k_zero_i32(int* __restrict__ p, int n) {
    int i = blockIdx.x * blockDim.x + threadIdx.x;
    if (i < n) p[i] = 0;
}

__global__ void k_hist(const int* __restrict__ dst, int* __restrict__ deg, int E) {
    int e = blockIdx.x * blockDim.x + threadIdx.x;
    if (e < E) atomicAdd(&deg[dst[e]], 1);
}

__global__ void k_dis(const int* __restrict__ deg, float* __restrict__ dis, int n) {
    int i = blockIdx.x * blockDim.x + threadIdx.x;
    if (i < n) dis[i] = rsqrtf(1.0f + (float)deg[i]);   // +1 self-loop
}

// scan stage 1: per-block (256) exclusive scan of deg -> rowp; block total -> bsum
__global__ __launch_bounds__(256) void k_scan1(const int* __restrict__ deg,
                                               int* __restrict__ rowp,
                                               int* __restrict__ bsum, int n) {
    __shared__ int s[256];
    int i = threadIdx.x;
    int gi = blockIdx.x * 256 + i;
    int v = (gi < n) ? deg[gi] : 0;
    s[i] = v;
    __syncthreads();
#pragma unroll
    for (int off = 1; off < 256; off <<= 1) {
        int t = (i >= off) ? s[i - off] : 0;
        __syncthreads();
        s[i] += t;
        __syncthreads();
    }
    if (gi < n) rowp[gi] = s[i] - v;                    // exclusive within block
    if (i == 255) bsum[blockIdx.x] = s[255];            // block total
}

// scan stage 2: single block of 512 scans the (<=512) block totals -> exclusive offsets
__global__ __launch_bounds__(512) void k_scan2(int* __restrict__ bsum, int nb) {
    __shared__ int s[512];
    int i = threadIdx.x;
    int v = (i < nb) ? bsum[i] : 0;
    s[i] = v;
    __syncthreads();
#pragma unroll
    for (int off = 1; off < 512; off <<= 1) {
        int t = (i >= off) ? s[i - off] : 0;
        __syncthreads();
        s[i] += t;
        __syncthreads();
    }
    if (i < nb) bsum[i] = s[i] - v;                     // exclusive block offset
}

// scan stage 3: add block offsets; init pos cursors; set rowp[N]=E
__global__ void k_scan3(int* __restrict__ rowp, int* __restrict__ pos,
                        const int* __restrict__ bsum, int n, int E) {
    int gi = blockIdx.x * blockDim.x + threadIdx.x;
    if (gi < n) {
        int r = rowp[gi] + bsum[blockIdx.x * blockDim.x / 256 + (threadIdx.x >= 0 ? 0 : 0)];
        // NOTE: blockDim must be 256 so block index maps 1:1 to scan1 blocks
        r = rowp[gi] + bsum[gi >> 8];
        rowp[gi] = r;
        pos[gi] = r;
    }
    if (gi == 0) rowp[n] = E;
}

// fill: slot = pos[dst]++; esrc[slot] = src
__global__ void k_fill(const int* __restrict__ src, const int* __restrict__ dst,
                       int* __restrict__ pos, int* __restrict__ esrc, int E) {
    int e = blockIdx.x * blockDim.x + threadIdx.x;
    if (e < E) {
        int d = dst[e];
        int slot = atomicAdd(&pos[d], 1);
        esrc[slot] = src[e];
    }
}

// ---- CSR aggregate: 16 lanes per node, self-loop fused as initializer -----
__global__ __launch_bounds__(256) void k_agg(const int* __restrict__ rowp,
                                             const int* __restrict__ esrc,
                                             const float* __restrict__ dis,
                                             const float* __restrict__ h,
                                             float* __restrict__ out, int n) {
    int tid = blockIdx.x * 256 + threadIdx.x;
    int node = tid >> 4;
    int c = tid & 15;
    if (node >= n) return;
    float dd = dis[node];
    float acc = dd * dd * h[(size_t)node * 16 + c];     // self-loop term
    int b = rowp[node], e = rowp[node + 1];
    for (int j = b; j < e; ++j) {
        int s = esrc[j];                                // sequential per row
        float w = dd * dis[s];
        acc = fmaf(w, h[(size_t)s * 16 + c], acc);      // 64B coalesced gather/group
    }
    out[(size_t)node * 16 + c] = acc;
}

// ---------------- fallback path (atomic scatter), proven correct -----------
__global__ void k_deg_init(float* __restrict__ deg, int n) {
    int i = blockIdx.x * blockDim.x + threadIdx.x;
    if (i < n) deg[i] = 1.0f;
}
__global__ void k_deg_count(const int* __restrict__ dst, float* __restrict__ deg, int E) {
    int e = blockIdx.x * blockDim.x + threadIdx.x;
    if (e < E) unsafeAtomicAdd(&deg[dst[e]], 1.0f);
}
__global__ void k_rsqrt(float* __restrict__ deg, int n) {
    int i = blockIdx.x * blockDim.x + threadIdx.x;
    if (i < n) deg[i] = rsqrtf(deg[i]);
}
__global__ void k_selfloop_init(const float* __restrict__ dis, const float* __restrict__ h,
                                float* __restrict__ out, int total) {
    int t = blockIdx.x * blockDim.x + threadIdx.x;
    if (t >= total) return;
    int i = t >> 4;
    float d = dis[i];
    out[t] = d * d * h[t];
}
__global__ __launch_bounds__(256) void k_scatter(const int* __restrict__ src,
                                                 const int* __restrict__ dst,
                                                 const float* __restrict__ dis,
                                                 const float* __restrict__ h,
                                                 float* __restrict__ out, int E) {
    int gid = blockIdx.x * 256 + threadIdx.x;
    int e = gid >> 4;
    if (e >= E) return;
    int c = gid & 15;
    int s = src[e];
    int d = dst[e];
    float v = dis[s] * dis[d] * h[(size_t)s * 16 + c];
    unsafeAtomicAdd(&out[(size_t)d * 16 + c], v);
}

extern "C" void kernel_launch(void* const* d_in, const int* in_sizes, int n_in,
                              void* d_out, int out_size, void* d_ws, size_t ws_size,
                              hipStream_t stream) {
    const float* x  = (const float*)d_in[0];
    const int*   ei = (const int*)d_in[1];        // [2, E] int32
    const float* W1 = (const float*)d_in[2];      // [512,16]
    const float* W2 = (const float*)d_in[3];      // [16,16]
    float* out = (float*)d_out;                   // [N,16]

    const int N = N_NODES;
    const int E = in_sizes[1] / 2;                // 3,200,000
    const int* src = ei;
    const int* dst = ei + E;
    const int B = 256;
    const int nb = (N + 255) / 256;               // 391 scan blocks (<=512)

    // ---- CSR workspace layout ----
    float* dis  = (float*)d_ws;
    float* bufA = dis + N;                        // h1, later h2
    float* bufB = bufA + (size_t)N * 16;          // a1 (layer-1 output)
    int* deg  = (int*)(bufB + (size_t)N * 16);
    int* rowp = deg + N;                          // N+1
    int* pos  = rowp + (N + 1);
    int* bsum = pos + N;                          // 512
    int* esrc = bsum + 512;                       // E
    size_t needed = (size_t)((char*)(esrc + E) - (char*)d_ws);

    if (ws_size >= needed) {
        // ---- CSR path ----
        k_zero_i32<<<(N + B - 1) / B, B, 0, stream>>>(deg, N);
        k_hist<<<(E + B - 1) / B, B, 0, stream>>>(dst, deg, E);
        k_dis<<<(N + B - 1) / B, B, 0, stream>>>(deg, dis, N);
        k_scan1<<<nb, 256, 0, stream>>>(deg, rowp, bsum, N);
        k_scan2<<<1, 512, 0, stream>>>(bsum, nb);
        k_scan3<<<nb, 256, 0, stream>>>(rowp, pos, bsum, N, E);
        k_fill<<<(E + B - 1) / B, B, 0, stream>>>(src, dst, pos, esrc, E);

        k_gemm1<<<(N + 15) / 16, B, 0, stream>>>(x, W1, bufA, N);
        k_agg<<<(N * 16 + B - 1) / B, B, 0, stream>>>(rowp, esrc, dis, bufA, bufB, N);
        k_gemm2<<<(N + 15) / 16, B, 0, stream>>>(bufB, W2, bufA, N);
        k_agg<<<(N * 16 + B - 1) / B, B, 0, stream>>>(rowp, esrc, dis, bufA, out, N);
    } else {
        // ---- fallback: atomic-scatter path (original, + new gemm1/gemm2) ----
        float* fdis = (float*)d_ws;
        float* h1   = fdis + N;
        float* out1 = h1 + (size_t)N * 16;
        float* h2   = out1 + (size_t)N * 16;
        const int NC = N * F_OUT;

        k_deg_init<<<(N + B - 1) / B, B, 0, stream>>>(fdis, N);
        k_deg_count<<<(E + B - 1) / B, B, 0, stream>>>(dst, fdis, E);
        k_rsqrt<<<(N + B - 1) / B, B, 0, stream>>>(fdis, N);

        k_gemm1<<<(N + 15) / 16, B, 0, stream>>>(x, W1, h1, N);
        k_selfloop_init<<<(NC + B - 1) / B, B, 0, stream>>>(fdis, h1, out1, NC);
        {
            long long threads = (long long)E * 16;
            k_scatter<<<(unsigned)((threads + B - 1) / B), B, 0, stream>>>(src, dst, fdis, h1, out1, E);
        }
        k_gemm2<<<(N + 15) / 16, B, 0, stream>>>(out1, W2, h2, N);
        k_selfloop_init<<<(NC + B - 1) / B, B, 0, stream>>>(fdis, h2, out, NC);
        {
            long long threads = (long long)E * 16;
            k_scatter<<<(unsigned)((threads + B - 1) / B), B, 0, stream>>>(src, dst, fdis, h2, out, E);
        }
    }
}